// Round 1
// baseline (1329.999 us; speedup 1.0000x reference)
//
#include <hip/hip_runtime.h>
#include <math.h>

// ---------------- problem constants ----------------
// base_feat [8,512,40,160] f32; rois [32,5]; T=64 (POOLED_W), N=32, C=512
// LSTM hidden 256, gates 1024; nclass 12; CTC S = 2*8+1 = 17.

#define TSTEPS 64
#define NSEQ   32
#define HID    256
#define GROWS  1024
#define FH     40
#define FW     160

// ---------------- workspace layout (floats) ----------------
#define OFF_RNN    0u            // [2048][1024]
#define OFF_XG     2097152u      // [2][1024][2048]
#define OFF_HCAT1  6291456u      // [2048][512]
#define OFF_H1     7340032u      // [2048][256]
#define OFF_HCAT2  7864320u      // [2048][512]
#define OFF_PREDS  8912896u      // [2048][12]
#define OFF_HT     8937472u      // [2 parity][2 dir][256][32]
#define OFF_CT     8970240u      // [2 dir][256][32]

// ---------------- ROI max pool -> rnn_in [t][n][c*2+ph] ----------------
__global__ __launch_bounds__(256) void roi_pool_kernel(
    const float* __restrict__ feat, const float* __restrict__ rois,
    float* __restrict__ rnn) {
  int n  = blockIdx.x;        // 0..31
  int cg = blockIdx.y;        // 0..255 (2 channels each)
  int tid = threadIdx.x;
  int pw = tid & 63, ph = (tid >> 6) & 1, cl = tid >> 7;
  int c = cg * 2 + cl;

  const float* r = rois + n * 5;
  int bi = (int)r[0];
  int x1 = (int)rintf(r[1] * (float)FW);
  int y1 = (int)rintf(r[2] * (float)FH);
  int x2 = (int)rintf(r[3] * (float)FW);
  int y2 = (int)rintf(r[4] * (float)FH);
  float rw = fmaxf((float)(x2 - x1 + 1), 1.0f);
  float rh = fmaxf((float)(y2 - y1 + 1), 1.0f);
  float bin_h = rh * 0.5f;
  float bin_w = rw * (1.0f / 64.0f);

  int hs = min(max((int)floorf((float)ph * bin_h) + y1, 0), FH);
  int he = min(max((int)ceilf((float)(ph + 1) * bin_h) + y1, 0), FH);
  int wst = min(max((int)floorf((float)pw * bin_w) + x1, 0), FW);
  int wen = min(max((int)ceilf((float)(pw + 1) * bin_w) + x1, 0), FW);

  float m = -1e30f;
  bool nonempty = (hs < he) && (wst < wen);
  const float* f = feat + ((size_t)bi * 512 + c) * (FH * FW);
  for (int h = hs; h < he; ++h) {
    const float* fr = f + h * FW;
    for (int w = wst; w < wen; ++w) m = fmaxf(m, fr[w]);
  }
  float out = nonempty ? m : 0.0f;
  rnn[((size_t)pw * NSEQ + n) * 1024 + c * 2 + ph] = out;
}

// ---------------- generic f32 GEMM: C[M][N] = A[M,K] * B[N,K]^T + bias ----------------
#define BM 64
#define BN 64
#define BK 16
#define APAD 4
__global__ __launch_bounds__(256) void gemm_nt(
    const float* __restrict__ A, const float* __restrict__ B,
    float* __restrict__ C, int M, int N, int K,
    const float* __restrict__ bm1, const float* __restrict__ bm2,
    const float* __restrict__ bn) {
  __shared__ float As[BK][BM + APAD];
  __shared__ float Bs[BK][BN + APAD];
  int m0 = blockIdx.y * BM, n0 = blockIdx.x * BN;
  int tid = threadIdx.x;
  int tm = tid & 15, tn = tid >> 4;
  float acc[4][4] = {};

  int lrow = tid >> 2;
  int lkq = (tid & 3) * 4;

  for (int k0 = 0; k0 < K; k0 += BK) {
    float4 va = *(const float4*)(A + (size_t)(m0 + lrow) * K + k0 + lkq);
    As[lkq + 0][lrow] = va.x; As[lkq + 1][lrow] = va.y;
    As[lkq + 2][lrow] = va.z; As[lkq + 3][lrow] = va.w;
    float4 vb = make_float4(0.f, 0.f, 0.f, 0.f);
    if (n0 + lrow < N) vb = *(const float4*)(B + (size_t)(n0 + lrow) * K + k0 + lkq);
    Bs[lkq + 0][lrow] = vb.x; Bs[lkq + 1][lrow] = vb.y;
    Bs[lkq + 2][lrow] = vb.z; Bs[lkq + 3][lrow] = vb.w;
    __syncthreads();
#pragma unroll
    for (int kk = 0; kk < BK; ++kk) {
      float a[4], b[4];
#pragma unroll
      for (int i = 0; i < 4; ++i) a[i] = As[kk][tm * 4 + i];
#pragma unroll
      for (int j = 0; j < 4; ++j) b[j] = Bs[kk][tn * 4 + j];
#pragma unroll
      for (int i = 0; i < 4; ++i)
#pragma unroll
        for (int j = 0; j < 4; ++j) acc[i][j] += a[i] * b[j];
    }
    __syncthreads();
  }

#pragma unroll
  for (int i = 0; i < 4; ++i) {
    int m = m0 + tm * 4 + i;
    float bmv = 0.0f;
    if (bm1) bmv += bm1[m];
    if (bm2) bmv += bm2[m];
#pragma unroll
    for (int j = 0; j < 4; ++j) {
      int n = n0 + tn * 4 + j;
      if (n < N) {
        float v = acc[i][j] + bmv;
        if (bn) v += bn[n];
        C[(size_t)m * N + n] = v;
      }
    }
  }
}

// ---------------- one LSTM time step (both directions) ----------------
// grid 256 blocks: blk>>7 = dir, blk&127 = h-group (2 h each)
// 256 threads: n = tid&31, hh = (tid>>5)&1, gate = tid>>6
__global__ __launch_bounds__(256) void lstm_step(
    const float* __restrict__ xgT,   // [2][1024][2048]  (row, t*32+n)
    const float* __restrict__ Wfw,   // [1024][256]
    const float* __restrict__ Wbw,
    const float* __restrict__ hT_rd, // [2][256][32]
    float* __restrict__ hT_wr,       // [2][256][32]
    float* __restrict__ cT,          // [2][256][32]
    float* __restrict__ hcat,        // [64][32][512]
    int s) {
  int blk = blockIdx.x;
  int dir = blk >> 7;
  int hg = blk & 127;
  int tid = threadIdx.x;
  int n = tid & 31, hh = (tid >> 5) & 1, gate = tid >> 6;
  int h = hg * 2 + hh;
  int row = gate * 256 + h;
  int t = (dir == 0) ? s : (63 - s);

  const float* W = (dir == 0 ? Wfw : Wbw) + (size_t)row * 256;
  float acc = xgT[((size_t)dir * GROWS + row) * 2048 + t * NSEQ + n];

  if (s > 0) {
    const float* hp = hT_rd + (size_t)dir * 256 * 32;
#pragma unroll 4
    for (int j = 0; j < 256; j += 4) {
      float4 w4 = *(const float4*)(W + j);
      acc += w4.x * hp[(j + 0) * 32 + n];
      acc += w4.y * hp[(j + 1) * 32 + n];
      acc += w4.z * hp[(j + 2) * 32 + n];
      acc += w4.w * hp[(j + 3) * 32 + n];
    }
  }

  __shared__ float gsm[4][2][32];
  gsm[gate][hh][n] = acc;
  __syncthreads();

  if (gate == 0) {
    float gi = gsm[0][hh][n], gf = gsm[1][hh][n];
    float gg = gsm[2][hh][n], go = gsm[3][hh][n];
    gi = 1.0f / (1.0f + expf(-gi));
    gf = 1.0f / (1.0f + expf(-gf));
    gg = tanhf(gg);
    go = 1.0f / (1.0f + expf(-go));
    int idx = (dir * 256 + h) * 32 + n;
    float c = (s > 0) ? cT[idx] : 0.0f;
    c = gf * c + gi * gg;
    float hn = go * tanhf(c);
    cT[idx] = c;
    hT_wr[idx] = hn;
    hcat[((size_t)t * NSEQ + n) * 512 + dir * 256 + h] = hn;
  }
}

// ---------------- fused log-softmax + CTC loss ----------------
#define CTC_S 17
__global__ __launch_bounds__(576) void ctc_kernel(
    const float* __restrict__ preds,   // [64][32][12]
    const int* __restrict__ text,      // [256]
    const int* __restrict__ text_len,  // [32]
    float* __restrict__ out) {
  __shared__ float alpha[NSEQ][CTC_S];
  __shared__ float nalpha[NSEQ][CTC_S];
  __shared__ float lse[NSEQ];
  __shared__ int ext[NSEQ][CTC_S];
  __shared__ unsigned char allow[NSEQ][CTC_S];
  __shared__ unsigned char validm[NSEQ][CTC_S];
  __shared__ int tlsh[NSEQ];
  __shared__ float logp_sh[NSEQ];

  int tid = threadIdx.x;
  int b = tid & 31, sIdx = tid >> 5;   // sIdx 0..17
  bool active = sIdx < CTC_S;

  if (tid < NSEQ) tlsh[tid] = text_len[tid];
  __syncthreads();

  if (active) {
    int tl = tlsh[b];
    int off = 0;
    for (int i = 0; i < b; ++i) off += tlsh[i];
    int e = 0;
    if (sIdx & 1) {
      int l = (sIdx - 1) >> 1;
      int idx = off + l;
      if (idx > 255) idx = 255;
      e = (l < tl) ? text[idx] : 0;
    }
    ext[b][sIdx] = e;
    validm[b][sIdx] = (sIdx < 2 * tl + 1) ? 1 : 0;
  }
  __syncthreads();
  if (active) {
    int e = ext[b][sIdx];
    bool same2 = (sIdx >= 2) && (e == ext[b][sIdx - 2]);
    allow[b][sIdx] = ((sIdx >= 2) && (e != 0) && !same2) ? 1 : 0;
  }
  // t = 0 log-softmax denom
  if (tid < NSEQ) {
    const float* p = preds + (size_t)b * 12;
    float mx = p[0];
    for (int k = 1; k < 12; ++k) mx = fmaxf(mx, p[k]);
    float ssum = 0.f;
    for (int k = 0; k < 12; ++k) ssum += expf(p[k] - mx);
    lse[b] = mx + logf(ssum);
  }
  __syncthreads();
  if (active) {
    float a = -1e30f;
    if (sIdx == 0) a = preds[(size_t)b * 12 + 0] - lse[b];
    else if (sIdx == 1 && tlsh[b] > 0) a = preds[(size_t)b * 12 + ext[b][1]] - lse[b];
    alpha[b][sIdx] = a;
  }
  __syncthreads();

  for (int t = 1; t < TSTEPS; ++t) {
    if (tid < NSEQ) {
      const float* p = preds + ((size_t)t * NSEQ + b) * 12;
      float mx = p[0];
      for (int k = 1; k < 12; ++k) mx = fmaxf(mx, p[k]);
      float ssum = 0.f;
      for (int k = 0; k < 12; ++k) ssum += expf(p[k] - mx);
      lse[b] = mx + logf(ssum);
    }
    __syncthreads();
    if (active) {
      float a = alpha[b][sIdx];
      float a1 = (sIdx >= 1) ? alpha[b][sIdx - 1] : -1e30f;
      float a2 = (sIdx >= 2 && allow[b][sIdx]) ? alpha[b][sIdx - 2] : -1e30f;
      float m = fmaxf(a, fmaxf(a1, a2));
      float ssum = expf(a - m) + expf(a1 - m) + expf(a2 - m);
      float emit = preds[((size_t)t * NSEQ + b) * 12 + ext[b][sIdx]] - lse[b];
      float nv = m + logf(ssum) + emit;
      nalpha[b][sIdx] = validm[b][sIdx] ? nv : -1e30f;
    }
    __syncthreads();
    if (active) alpha[b][sIdx] = nalpha[b][sIdx];
    __syncthreads();
  }

  if (tid < NSEQ) {
    int tl = tlsh[b];
    float a1 = alpha[b][2 * tl];
    float a2 = (tl > 0) ? alpha[b][2 * tl - 1] : -1e30f;
    float m = fmaxf(a1, a2);
    logp_sh[b] = m + logf(expf(a1 - m) + expf(a2 - m));
  }
  __syncthreads();
  if (tid == 0) {
    float ssum = 0.f;
    for (int i = 0; i < NSEQ; ++i) ssum += logp_sh[i];
    out[0] = -ssum / (float)NSEQ;
  }
}

// ---------------- launch ----------------
extern "C" void kernel_launch(void* const* d_in, const int* in_sizes, int n_in,
                              void* d_out, int out_size, void* d_ws, size_t ws_size,
                              hipStream_t stream) {
  (void)in_sizes; (void)n_in; (void)out_size; (void)ws_size;
  const float* base_feat = (const float*)d_in[0];
  const int* text = (const int*)d_in[1];
  const int* text_len = (const int*)d_in[2];
  const float* rois = (const float*)d_in[3];
  const float* l1_fw_W_ih = (const float*)d_in[4];
  const float* l1_fw_W_hh = (const float*)d_in[5];
  const float* l1_fw_b_ih = (const float*)d_in[6];
  const float* l1_fw_b_hh = (const float*)d_in[7];
  const float* l1_bw_W_ih = (const float*)d_in[8];
  const float* l1_bw_W_hh = (const float*)d_in[9];
  const float* l1_bw_b_ih = (const float*)d_in[10];
  const float* l1_bw_b_hh = (const float*)d_in[11];
  const float* l2_fw_W_ih = (const float*)d_in[12];
  const float* l2_fw_W_hh = (const float*)d_in[13];
  const float* l2_fw_b_ih = (const float*)d_in[14];
  const float* l2_fw_b_hh = (const float*)d_in[15];
  const float* l2_bw_W_ih = (const float*)d_in[16];
  const float* l2_bw_W_hh = (const float*)d_in[17];
  const float* l2_bw_b_ih = (const float*)d_in[18];
  const float* l2_bw_b_hh = (const float*)d_in[19];
  const float* W_emb1 = (const float*)d_in[20];
  const float* b_emb1 = (const float*)d_in[21];
  const float* W_emb2 = (const float*)d_in[22];
  const float* b_emb2 = (const float*)d_in[23];

  float* ws = (float*)d_ws;
  float* rnn   = ws + OFF_RNN;
  float* xg    = ws + OFF_XG;
  float* hcat1 = ws + OFF_HCAT1;
  float* h1    = ws + OFF_H1;
  float* hcat2 = ws + OFF_HCAT2;
  float* preds = ws + OFF_PREDS;
  float* hT    = ws + OFF_HT;   // [2 parity][2 dir][256][32]
  float* cT    = ws + OFF_CT;

  // 1) ROI max pool -> rnn_in [2048][1024]
  roi_pool_kernel<<<dim3(32, 256), 256, 0, stream>>>(base_feat, rois, rnn);

  // 2) xg layer1: [1024][2048] per dir = W_ih * rnn^T + (b_ih + b_hh)
  gemm_nt<<<dim3(32, 16), 256, 0, stream>>>(l1_fw_W_ih, rnn, xg,
      1024, 2048, 1024, l1_fw_b_ih, l1_fw_b_hh, nullptr);
  gemm_nt<<<dim3(32, 16), 256, 0, stream>>>(l1_bw_W_ih, rnn, xg + 2097152u,
      1024, 2048, 1024, l1_bw_b_ih, l1_bw_b_hh, nullptr);

  // 3) layer-1 recurrence (64 steps, both directions)
  for (int s = 0; s < 64; ++s) {
    lstm_step<<<256, 256, 0, stream>>>(xg, l1_fw_W_hh, l1_bw_W_hh,
        hT + (size_t)((s + 1) & 1) * 16384u, hT + (size_t)(s & 1) * 16384u,
        cT, hcat1, s);
  }

  // 4) h1 = hcat1 @ W_emb1^T + b_emb1  -> [2048][256]
  gemm_nt<<<dim3(4, 32), 256, 0, stream>>>(hcat1, W_emb1, h1,
      2048, 256, 512, nullptr, nullptr, b_emb1);

  // 5) xg layer2
  gemm_nt<<<dim3(32, 16), 256, 0, stream>>>(l2_fw_W_ih, h1, xg,
      1024, 2048, 256, l2_fw_b_ih, l2_fw_b_hh, nullptr);
  gemm_nt<<<dim3(32, 16), 256, 0, stream>>>(l2_bw_W_ih, h1, xg + 2097152u,
      1024, 2048, 256, l2_bw_b_ih, l2_bw_b_hh, nullptr);

  // 6) layer-2 recurrence
  for (int s = 0; s < 64; ++s) {
    lstm_step<<<256, 256, 0, stream>>>(xg, l2_fw_W_hh, l2_bw_W_hh,
        hT + (size_t)((s + 1) & 1) * 16384u, hT + (size_t)(s & 1) * 16384u,
        cT, hcat2, s);
  }

  // 7) preds = hcat2 @ W_emb2^T + b_emb2 -> [2048][12]
  gemm_nt<<<dim3(1, 32), 256, 0, stream>>>(hcat2, W_emb2, preds,
      2048, 12, 512, nullptr, nullptr, b_emb2);

  // 8) log-softmax + CTC
  ctc_kernel<<<1, 576, 0, stream>>>(preds, text, text_len, (float*)d_out);
}

// Round 2
// 1031.718 us; speedup vs baseline: 1.2891x; 1.2891x over previous
//
#include <hip/hip_runtime.h>
#include <math.h>

// ---------------- problem constants ----------------
#define TSTEPS 64
#define NSEQ   32
#define HID    256
#define GROWS  1024
#define FH     40
#define FW     160

// ---------------- workspace layout (floats) ----------------
#define OFF_RNN    0u            // [2048][1024]
#define OFF_XG     2097152u      // [2][1024][2048]
#define OFF_HCAT1  6291456u      // [2048][512]
#define OFF_H1     7340032u      // [2048][256]
#define OFF_HCAT2  7864320u      // [2048][512]
#define OFF_PREDS  8912896u      // [2048][12]
#define OFF_BAR    8937472u      // 2 ints (grid barrier counters)

typedef __attribute__((ext_vector_type(8))) short short8;
typedef __attribute__((ext_vector_type(4))) float f32x4;

static __device__ inline short bf16c(float x) {
  union { float f; unsigned u; } v; v.f = x;
  unsigned r = v.u + 0x7fff + ((v.u >> 16) & 1);   // RNE
  return (short)(r >> 16);
}

// ---------------- ROI max pool -> rnn_in [t][n][c*2+ph] ----------------
__global__ __launch_bounds__(256) void roi_pool_kernel(
    const float* __restrict__ feat, const float* __restrict__ rois,
    float* __restrict__ rnn) {
  int n  = blockIdx.x;
  int cg = blockIdx.y;
  int tid = threadIdx.x;
  int pw = tid & 63, ph = (tid >> 6) & 1, cl = tid >> 7;
  int c = cg * 2 + cl;

  const float* r = rois + n * 5;
  int bi = (int)r[0];
  int x1 = (int)rintf(r[1] * (float)FW);
  int y1 = (int)rintf(r[2] * (float)FH);
  int x2 = (int)rintf(r[3] * (float)FW);
  int y2 = (int)rintf(r[4] * (float)FH);
  float rw = fmaxf((float)(x2 - x1 + 1), 1.0f);
  float rh = fmaxf((float)(y2 - y1 + 1), 1.0f);
  float bin_h = rh * 0.5f;
  float bin_w = rw * (1.0f / 64.0f);

  int hs = min(max((int)floorf((float)ph * bin_h) + y1, 0), FH);
  int he = min(max((int)ceilf((float)(ph + 1) * bin_h) + y1, 0), FH);
  int wst = min(max((int)floorf((float)pw * bin_w) + x1, 0), FW);
  int wen = min(max((int)ceilf((float)(pw + 1) * bin_w) + x1, 0), FW);

  float m = -1e30f;
  bool nonempty = (hs < he) && (wst < wen);
  const float* f = feat + ((size_t)bi * 512 + c) * (FH * FW);
  for (int h = hs; h < he; ++h) {
    const float* fr = f + h * FW;
    for (int w = wst; w < wen; ++w) m = fmaxf(m, fr[w]);
  }
  float out = nonempty ? m : 0.0f;
  rnn[((size_t)pw * NSEQ + n) * 1024 + c * 2 + ph] = out;
}

// ---------------- generic f32 GEMM: C[M][N] = A[M,K] * B[N,K]^T + bias ----------------
#define BM 64
#define BN 64
#define BK 16
#define APAD 4
__global__ __launch_bounds__(256) void gemm_nt(
    const float* __restrict__ A, const float* __restrict__ B,
    float* __restrict__ C, int M, int N, int K,
    const float* __restrict__ bm1, const float* __restrict__ bm2,
    const float* __restrict__ bn) {
  __shared__ float As[BK][BM + APAD];
  __shared__ float Bs[BK][BN + APAD];
  int m0 = blockIdx.y * BM, n0 = blockIdx.x * BN;
  int tid = threadIdx.x;
  int tm = tid & 15, tn = tid >> 4;
  float acc[4][4] = {};

  int lrow = tid >> 2;
  int lkq = (tid & 3) * 4;

  for (int k0 = 0; k0 < K; k0 += BK) {
    float4 va = *(const float4*)(A + (size_t)(m0 + lrow) * K + k0 + lkq);
    As[lkq + 0][lrow] = va.x; As[lkq + 1][lrow] = va.y;
    As[lkq + 2][lrow] = va.z; As[lkq + 3][lrow] = va.w;
    float4 vb = make_float4(0.f, 0.f, 0.f, 0.f);
    if (n0 + lrow < N) vb = *(const float4*)(B + (size_t)(n0 + lrow) * K + k0 + lkq);
    Bs[lkq + 0][lrow] = vb.x; Bs[lkq + 1][lrow] = vb.y;
    Bs[lkq + 2][lrow] = vb.z; Bs[lkq + 3][lrow] = vb.w;
    __syncthreads();
#pragma unroll
    for (int kk = 0; kk < BK; ++kk) {
      float a[4], b[4];
#pragma unroll
      for (int i = 0; i < 4; ++i) a[i] = As[kk][tm * 4 + i];
#pragma unroll
      for (int j = 0; j < 4; ++j) b[j] = Bs[kk][tn * 4 + j];
#pragma unroll
      for (int i = 0; i < 4; ++i)
#pragma unroll
        for (int j = 0; j < 4; ++j) acc[i][j] += a[i] * b[j];
    }
    __syncthreads();
  }

#pragma unroll
  for (int i = 0; i < 4; ++i) {
    int m = m0 + tm * 4 + i;
    float bmv = 0.0f;
    if (bm1) bmv += bm1[m];
    if (bm2) bmv += bm2[m];
#pragma unroll
    for (int j = 0; j < 4; ++j) {
      int n = n0 + tn * 4 + j;
      if (n < N) {
        float v = acc[i][j] + bmv;
        if (bn) v += bn[n];
        C[(size_t)m * N + n] = v;
      }
    }
  }
}

// ---------------- persistent BiLSTM layer (one launch per layer) ----------------
// Grid: 16 blocks x 256 threads. blk>>3 = dir, blk&7 = unit-quad (32 units).
// W_hh held in registers as bf16 MFMA A-fragments for all 64 steps.
// Tile rows are gate-interleaved: tile-row r -> (gate=r&3, unit_off=r>>2), so
// each lane's 4 C-regs are i,f,g,o of one (unit,n); c-state stays in registers.
// h exchanged between blocks through hcat (f32), staged to XOR-swizzled LDS.
#define LSTM_BLOCKS 16
__global__ __launch_bounds__(256) void lstm_layer(
    const float* __restrict__ xgT,   // [2][1024][2048] (row, t*32+n)
    const float* __restrict__ Wfw,   // [1024][256]
    const float* __restrict__ Wbw,
    float* __restrict__ hcat,        // [64][32][512]
    int* __restrict__ bar) {
  const int blk = blockIdx.x;
  const int dir = blk >> 3;
  const int u0 = (blk & 7) * 32;
  const int tid = threadIdx.x;
  const int w = tid >> 6;
  const int l = tid & 63;
  const int ln15 = l & 15;
  const int kg = l >> 4;            // 0..3
  const int u_wave = u0 + w * 8;

  __shared__ unsigned short h_lds[32 * 256];  // [n][k] bf16, XOR-swizzled 16B slots
  __shared__ float h_ex[32][32];              // [unit_local][n]

  // ---- load W_hh A-fragments into registers (once) ----
  const float* Wh = dir ? Wbw : Wfw;
  short8 afrag[2][8];
  {
    int r = ln15;
    int gate = r & 3, du = r >> 2;
#pragma unroll
    for (int mt = 0; mt < 2; ++mt) {
      int unit = u_wave + mt * 4 + du;
      int row = gate * 256 + unit;
#pragma unroll
      for (int kc = 0; kc < 8; ++kc) {
        int k = kc * 32 + kg * 8;
        const float* src = Wh + (size_t)row * 256 + k;
        short8 f;
#pragma unroll
        for (int j = 0; j < 8; ++j) f[j] = bf16c(src[j]);
        afrag[mt][kc] = f;
      }
    }
  }

  const float* xgd = xgT + (size_t)dir * GROWS * 2048;
  float cst[2][2] = {{0.f, 0.f}, {0.f, 0.f}};

  // staging indices (thread t: n = t>>3, k0 = (t&7)*32)
  const int st_n = tid >> 3;
  const int st_k0 = (tid & 7) * 32;
  // writer indices (thread t: n = t&31, uc = t>>5)
  const int wr_n = tid & 31;
  const int wr_uc = tid >> 5;

  for (int s = 0; s < TSTEPS; ++s) {
    const int t = dir ? (63 - s) : s;

    if (s > 0) {
      const int t_prev = dir ? (t + 1) : (t - 1);
      const float* src = hcat + ((size_t)t_prev * NSEQ + st_n) * 512 + dir * 256 + st_k0;
      char* dst_row = (char*)h_lds + st_n * 512;
      int swz = (st_n & 7) << 4;
#pragma unroll
      for (int c = 0; c < 4; ++c) {
        float4 a = *(const float4*)(src + c * 8);
        float4 b = *(const float4*)(src + c * 8 + 4);
        short8 u;
        u[0] = bf16c(a.x); u[1] = bf16c(a.y); u[2] = bf16c(a.z); u[3] = bf16c(a.w);
        u[4] = bf16c(b.x); u[5] = bf16c(b.y); u[6] = bf16c(b.z); u[7] = bf16c(b.w);
        *(short8*)(dst_row + ((st_k0 * 2 + c * 16) ^ swz)) = u;
      }
    }
    __syncthreads();

    // ---- acc init from xg ----
    f32x4 acc[2][2];
#pragma unroll
    for (int mt = 0; mt < 2; ++mt) {
      int unit = u_wave + mt * 4 + kg;
#pragma unroll
      for (int nt = 0; nt < 2; ++nt) {
        int n = nt * 16 + ln15;
        const float* xp = xgd + (size_t)unit * 2048 + (size_t)t * NSEQ + n;
#pragma unroll
        for (int j = 0; j < 4; ++j)
          acc[mt][nt][j] = xp[(size_t)j * 256 * 2048];
      }
    }

    // ---- MFMA: gates += W_hh * h_prev ----
    if (s > 0) {
#pragma unroll
      for (int kc = 0; kc < 8; ++kc) {
        int kbyte = kc * 64 + kg * 16;
        int n0r = ln15, n1r = 16 + ln15;
        short8 b0 = *(const short8*)((const char*)h_lds + n0r * 512 + (kbyte ^ ((n0r & 7) << 4)));
        short8 b1 = *(const short8*)((const char*)h_lds + n1r * 512 + (kbyte ^ ((n1r & 7) << 4)));
        acc[0][0] = __builtin_amdgcn_mfma_f32_16x16x32_bf16(afrag[0][kc], b0, acc[0][0], 0, 0, 0);
        acc[0][1] = __builtin_amdgcn_mfma_f32_16x16x32_bf16(afrag[0][kc], b1, acc[0][1], 0, 0, 0);
        acc[1][0] = __builtin_amdgcn_mfma_f32_16x16x32_bf16(afrag[1][kc], b0, acc[1][0], 0, 0, 0);
        acc[1][1] = __builtin_amdgcn_mfma_f32_16x16x32_bf16(afrag[1][kc], b1, acc[1][1], 0, 0, 0);
      }
    }

    // ---- elementwise LSTM cell (lane-local; c in registers) ----
#pragma unroll
    for (int mt = 0; mt < 2; ++mt) {
#pragma unroll
      for (int nt = 0; nt < 2; ++nt) {
        float gi = acc[mt][nt][0], gf = acc[mt][nt][1];
        float gg = acc[mt][nt][2], go = acc[mt][nt][3];
        gi = 1.0f / (1.0f + expf(-gi));
        gf = 1.0f / (1.0f + expf(-gf));
        gg = tanhf(gg);
        go = 1.0f / (1.0f + expf(-go));
        float c = gf * cst[mt][nt] + gi * gg;
        cst[mt][nt] = c;
        float h = go * tanhf(c);
        h_ex[w * 8 + mt * 4 + kg][nt * 16 + ln15] = h;
      }
    }
    __syncthreads();

    // ---- coalesced hcat write (also the inter-block h exchange medium) ----
    {
      float4 hv;
      hv.x = h_ex[wr_uc * 4 + 0][wr_n];
      hv.y = h_ex[wr_uc * 4 + 1][wr_n];
      hv.z = h_ex[wr_uc * 4 + 2][wr_n];
      hv.w = h_ex[wr_uc * 4 + 3][wr_n];
      *(float4*)(hcat + ((size_t)t * NSEQ + wr_n) * 512 + dir * 256 + u0 + wr_uc * 4) = hv;
    }

    // ---- grid barrier (generation-counting, device scope) ----
    if (s < TSTEPS - 1) {
      __syncthreads();
      if (tid == 0) {
        __hip_atomic_fetch_add(bar, 1, __ATOMIC_ACQ_REL, __HIP_MEMORY_SCOPE_AGENT);
        int target = LSTM_BLOCKS * (s + 1);
        while (__hip_atomic_load(bar, __ATOMIC_ACQUIRE, __HIP_MEMORY_SCOPE_AGENT) < target) {
          __builtin_amdgcn_s_sleep(1);
        }
      }
      __syncthreads();
    }
  }
}

// ---------------- fused log-softmax + CTC loss ----------------
#define CTC_S 17
__global__ __launch_bounds__(576) void ctc_kernel(
    const float* __restrict__ preds,   // [64][32][12]
    const int* __restrict__ text,      // [256]
    const int* __restrict__ text_len,  // [32]
    float* __restrict__ out) {
  __shared__ float alpha[NSEQ][CTC_S];
  __shared__ float nalpha[NSEQ][CTC_S];
  __shared__ float lse[NSEQ];
  __shared__ int ext[NSEQ][CTC_S];
  __shared__ unsigned char allow[NSEQ][CTC_S];
  __shared__ unsigned char validm[NSEQ][CTC_S];
  __shared__ int tlsh[NSEQ];
  __shared__ float logp_sh[NSEQ];

  int tid = threadIdx.x;
  int b = tid & 31, sIdx = tid >> 5;
  bool active = sIdx < CTC_S;

  if (tid < NSEQ) tlsh[tid] = text_len[tid];
  __syncthreads();

  if (active) {
    int tl = tlsh[b];
    int off = 0;
    for (int i = 0; i < b; ++i) off += tlsh[i];
    int e = 0;
    if (sIdx & 1) {
      int lbl = (sIdx - 1) >> 1;
      int idx = off + lbl;
      if (idx > 255) idx = 255;
      e = (lbl < tl) ? text[idx] : 0;
    }
    ext[b][sIdx] = e;
    validm[b][sIdx] = (sIdx < 2 * tl + 1) ? 1 : 0;
  }
  __syncthreads();
  if (active) {
    int e = ext[b][sIdx];
    bool same2 = (sIdx >= 2) && (e == ext[b][sIdx - 2]);
    allow[b][sIdx] = ((sIdx >= 2) && (e != 0) && !same2) ? 1 : 0;
  }
  if (tid < NSEQ) {
    const float* p = preds + (size_t)b * 12;
    float mx = p[0];
    for (int k = 1; k < 12; ++k) mx = fmaxf(mx, p[k]);
    float ssum = 0.f;
    for (int k = 0; k < 12; ++k) ssum += expf(p[k] - mx);
    lse[b] = mx + logf(ssum);
  }
  __syncthreads();
  if (active) {
    float a = -1e30f;
    if (sIdx == 0) a = preds[(size_t)b * 12 + 0] - lse[b];
    else if (sIdx == 1 && tlsh[b] > 0) a = preds[(size_t)b * 12 + ext[b][1]] - lse[b];
    alpha[b][sIdx] = a;
  }
  __syncthreads();

  for (int t = 1; t < TSTEPS; ++t) {
    if (tid < NSEQ) {
      const float* p = preds + ((size_t)t * NSEQ + b) * 12;
      float mx = p[0];
      for (int k = 1; k < 12; ++k) mx = fmaxf(mx, p[k]);
      float ssum = 0.f;
      for (int k = 0; k < 12; ++k) ssum += expf(p[k] - mx);
      lse[b] = mx + logf(ssum);
    }
    __syncthreads();
    if (active) {
      float a = alpha[b][sIdx];
      float a1 = (sIdx >= 1) ? alpha[b][sIdx - 1] : -1e30f;
      float a2 = (sIdx >= 2 && allow[b][sIdx]) ? alpha[b][sIdx - 2] : -1e30f;
      float m = fmaxf(a, fmaxf(a1, a2));
      float ssum = expf(a - m) + expf(a1 - m) + expf(a2 - m);
      float emit = preds[((size_t)t * NSEQ + b) * 12 + ext[b][sIdx]] - lse[b];
      float nv = m + logf(ssum) + emit;
      nalpha[b][sIdx] = validm[b][sIdx] ? nv : -1e30f;
    }
    __syncthreads();
    if (active) alpha[b][sIdx] = nalpha[b][sIdx];
    __syncthreads();
  }

  if (tid < NSEQ) {
    int tl = tlsh[b];
    float a1 = alpha[b][2 * tl];
    float a2 = (tl > 0) ? alpha[b][2 * tl - 1] : -1e30f;
    float m = fmaxf(a1, a2);
    logp_sh[b] = m + logf(expf(a1 - m) + expf(a2 - m));
  }
  __syncthreads();
  if (tid == 0) {
    float ssum = 0.f;
    for (int i = 0; i < NSEQ; ++i) ssum += logp_sh[i];
    out[0] = -ssum / (float)NSEQ;
  }
}

// ---------------- launch ----------------
extern "C" void kernel_launch(void* const* d_in, const int* in_sizes, int n_in,
                              void* d_out, int out_size, void* d_ws, size_t ws_size,
                              hipStream_t stream) {
  (void)in_sizes; (void)n_in; (void)out_size; (void)ws_size;
  const float* base_feat = (const float*)d_in[0];
  const int* text = (const int*)d_in[1];
  const int* text_len = (const int*)d_in[2];
  const float* rois = (const float*)d_in[3];
  const float* l1_fw_W_ih = (const float*)d_in[4];
  const float* l1_fw_W_hh = (const float*)d_in[5];
  const float* l1_fw_b_ih = (const float*)d_in[6];
  const float* l1_fw_b_hh = (const float*)d_in[7];
  const float* l1_bw_W_ih = (const float*)d_in[8];
  const float* l1_bw_W_hh = (const float*)d_in[9];
  const float* l1_bw_b_ih = (const float*)d_in[10];
  const float* l1_bw_b_hh = (const float*)d_in[11];
  const float* l2_fw_W_ih = (const float*)d_in[12];
  const float* l2_fw_W_hh = (const float*)d_in[13];
  const float* l2_fw_b_ih = (const float*)d_in[14];
  const float* l2_fw_b_hh = (const float*)d_in[15];
  const float* l2_bw_W_ih = (const float*)d_in[16];
  const float* l2_bw_W_hh = (const float*)d_in[17];
  const float* l2_bw_b_ih = (const float*)d_in[18];
  const float* l2_bw_b_hh = (const float*)d_in[19];
  const float* W_emb1 = (const float*)d_in[20];
  const float* b_emb1 = (const float*)d_in[21];
  const float* W_emb2 = (const float*)d_in[22];
  const float* b_emb2 = (const float*)d_in[23];

  float* ws = (float*)d_ws;
  float* rnn   = ws + OFF_RNN;
  float* xg    = ws + OFF_XG;
  float* hcat1 = ws + OFF_HCAT1;
  float* h1    = ws + OFF_H1;
  float* hcat2 = ws + OFF_HCAT2;
  float* preds = ws + OFF_PREDS;
  int*   bar   = (int*)(ws + OFF_BAR);

  hipMemsetAsync(bar, 0, 2 * sizeof(int), stream);

  // 1) ROI max pool -> rnn_in [2048][1024]
  roi_pool_kernel<<<dim3(32, 256), 256, 0, stream>>>(base_feat, rois, rnn);

  // 2) xg layer1
  gemm_nt<<<dim3(32, 16), 256, 0, stream>>>(l1_fw_W_ih, rnn, xg,
      1024, 2048, 1024, l1_fw_b_ih, l1_fw_b_hh, nullptr);
  gemm_nt<<<dim3(32, 16), 256, 0, stream>>>(l1_bw_W_ih, rnn, xg + 2097152u,
      1024, 2048, 1024, l1_bw_b_ih, l1_bw_b_hh, nullptr);

  // 3) layer-1 recurrence (persistent, 1 launch)
  lstm_layer<<<LSTM_BLOCKS, 256, 0, stream>>>(xg, l1_fw_W_hh, l1_bw_W_hh, hcat1, bar);

  // 4) h1 = hcat1 @ W_emb1^T + b_emb1
  gemm_nt<<<dim3(4, 32), 256, 0, stream>>>(hcat1, W_emb1, h1,
      2048, 256, 512, nullptr, nullptr, b_emb1);

  // 5) xg layer2
  gemm_nt<<<dim3(32, 16), 256, 0, stream>>>(l2_fw_W_ih, h1, xg,
      1024, 2048, 256, l2_fw_b_ih, l2_fw_b_hh, nullptr);
  gemm_nt<<<dim3(32, 16), 256, 0, stream>>>(l2_bw_W_ih, h1, xg + 2097152u,
      1024, 2048, 256, l2_bw_b_ih, l2_bw_b_hh, nullptr);

  // 6) layer-2 recurrence
  lstm_layer<<<LSTM_BLOCKS, 256, 0, stream>>>(xg, l2_fw_W_hh, l2_bw_W_hh, hcat2, bar + 1);

  // 7) preds = hcat2 @ W_emb2^T + b_emb2
  gemm_nt<<<dim3(1, 32), 256, 0, stream>>>(hcat2, W_emb2, preds,
      2048, 12, 512, nullptr, nullptr, b_emb2);

  // 8) log-softmax + CTC
  ctc_kernel<<<1, 576, 0, stream>>>(preds, text, text_len, (float*)d_out);
}

// Round 3
// 984.071 us; speedup vs baseline: 1.3515x; 1.0484x over previous
//
#include <hip/hip_runtime.h>
#include <math.h>

// ---------------- problem constants ----------------
#define TSTEPS 64
#define NSEQ   32
#define HID    256
#define GROWS  1024
#define FH     40
#define FW     160

// ---------------- workspace layout (floats) ----------------
#define OFF_RNN    0u            // [2048][1024]
#define OFF_XG     2097152u      // [2][1024][2048]
#define OFF_HCAT1  6291456u      // [2048][512]
#define OFF_H1     7340032u      // [2048][256]
#define OFF_HCAT2  7864320u      // [2048][512]
#define OFF_PREDS  8912896u      // [2048][12]
#define OFF_BAR    8937472u      // 16 ints (flag words)

typedef __attribute__((ext_vector_type(8))) short short8;
typedef __attribute__((ext_vector_type(4))) float f32x4;

static __device__ inline short bf16c(float x) {
  union { float f; unsigned u; } v; v.f = x;
  unsigned r = v.u + 0x7fff + ((v.u >> 16) & 1);   // RNE
  return (short)(r >> 16);
}

// fast sigmoid/tanh via v_exp_f32 + v_rcp_f32 (limits correct at +-inf)
static __device__ inline float sigm(float x) {
  return __builtin_amdgcn_rcpf(1.0f + __expf(-x));
}
static __device__ inline float tanh_fast(float x) {
  return 1.0f - 2.0f * __builtin_amdgcn_rcpf(1.0f + __expf(2.0f * x));
}

// ---------------- ROI max pool -> rnn_in [t][n][c*2+ph] ----------------
__global__ __launch_bounds__(256) void roi_pool_kernel(
    const float* __restrict__ feat, const float* __restrict__ rois,
    float* __restrict__ rnn) {
  int n  = blockIdx.x;
  int cg = blockIdx.y;
  int tid = threadIdx.x;
  int pw = tid & 63, ph = (tid >> 6) & 1, cl = tid >> 7;
  int c = cg * 2 + cl;

  const float* r = rois + n * 5;
  int bi = (int)r[0];
  int x1 = (int)rintf(r[1] * (float)FW);
  int y1 = (int)rintf(r[2] * (float)FH);
  int x2 = (int)rintf(r[3] * (float)FW);
  int y2 = (int)rintf(r[4] * (float)FH);
  float rw = fmaxf((float)(x2 - x1 + 1), 1.0f);
  float rh = fmaxf((float)(y2 - y1 + 1), 1.0f);
  float bin_h = rh * 0.5f;
  float bin_w = rw * (1.0f / 64.0f);

  int hs = min(max((int)floorf((float)ph * bin_h) + y1, 0), FH);
  int he = min(max((int)ceilf((float)(ph + 1) * bin_h) + y1, 0), FH);
  int wst = min(max((int)floorf((float)pw * bin_w) + x1, 0), FW);
  int wen = min(max((int)ceilf((float)(pw + 1) * bin_w) + x1, 0), FW);

  float m = -1e30f;
  bool nonempty = (hs < he) && (wst < wen);
  const float* f = feat + ((size_t)bi * 512 + c) * (FH * FW);
  for (int h = hs; h < he; ++h) {
    const float* fr = f + h * FW;
    for (int w = wst; w < wen; ++w) m = fmaxf(m, fr[w]);
  }
  float out = nonempty ? m : 0.0f;
  rnn[((size_t)pw * NSEQ + n) * 1024 + c * 2 + ph] = out;
}

// ---------------- generic f32 GEMM: C[M][N] = A[M,K] * B[N,K]^T + bias ----------------
#define BM 64
#define BN 64
#define BK 16
#define APAD 4
__global__ __launch_bounds__(256) void gemm_nt(
    const float* __restrict__ A, const float* __restrict__ B,
    float* __restrict__ C, int M, int N, int K,
    const float* __restrict__ bm1, const float* __restrict__ bm2,
    const float* __restrict__ bn) {
  __shared__ float As[BK][BM + APAD];
  __shared__ float Bs[BK][BN + APAD];
  int m0 = blockIdx.y * BM, n0 = blockIdx.x * BN;
  int tid = threadIdx.x;
  int tm = tid & 15, tn = tid >> 4;
  float acc[4][4] = {};

  int lrow = tid >> 2;
  int lkq = (tid & 3) * 4;

  for (int k0 = 0; k0 < K; k0 += BK) {
    float4 va = *(const float4*)(A + (size_t)(m0 + lrow) * K + k0 + lkq);
    As[lkq + 0][lrow] = va.x; As[lkq + 1][lrow] = va.y;
    As[lkq + 2][lrow] = va.z; As[lkq + 3][lrow] = va.w;
    float4 vb = make_float4(0.f, 0.f, 0.f, 0.f);
    if (n0 + lrow < N) vb = *(const float4*)(B + (size_t)(n0 + lrow) * K + k0 + lkq);
    Bs[lkq + 0][lrow] = vb.x; Bs[lkq + 1][lrow] = vb.y;
    Bs[lkq + 2][lrow] = vb.z; Bs[lkq + 3][lrow] = vb.w;
    __syncthreads();
#pragma unroll
    for (int kk = 0; kk < BK; ++kk) {
      float a[4], b[4];
#pragma unroll
      for (int i = 0; i < 4; ++i) a[i] = As[kk][tm * 4 + i];
#pragma unroll
      for (int j = 0; j < 4; ++j) b[j] = Bs[kk][tn * 4 + j];
#pragma unroll
      for (int i = 0; i < 4; ++i)
#pragma unroll
        for (int j = 0; j < 4; ++j) acc[i][j] += a[i] * b[j];
    }
    __syncthreads();
  }

#pragma unroll
  for (int i = 0; i < 4; ++i) {
    int m = m0 + tm * 4 + i;
    float bmv = 0.0f;
    if (bm1) bmv += bm1[m];
    if (bm2) bmv += bm2[m];
#pragma unroll
    for (int j = 0; j < 4; ++j) {
      int n = n0 + tn * 4 + j;
      if (n < N) {
        float v = acc[i][j] + bmv;
        if (bn) v += bn[n];
        C[(size_t)m * N + n] = v;
      }
    }
  }
}

// ---------------- persistent BiLSTM layer: 4 blocks (2 per direction) ----------------
// blk>>1 = dir, blk&1 = half (units half*128..+128). 512 threads = 8 waves.
// Each wave owns 16 units x 4 gates = 64 weight rows, held in registers as
// bf16 MFMA A-fragments (128 VGPR/lane). 2-party barrier per direction:
// per-block flag words, release-store own / acquire-poll peer.
__global__ __launch_bounds__(512, 2) void lstm_layer2(
    const float* __restrict__ xgT,   // [2][1024][2048]  (row, t*32+n)
    const float* __restrict__ Wfw,   // [1024][256]
    const float* __restrict__ Wbw,
    float* __restrict__ hcat,        // [64][32][512]
    int* __restrict__ flags) {       // 4 ints: [dir*2+half]
  const int dir = blockIdx.x >> 1;
  const int half = blockIdx.x & 1;
  const int tid = threadIdx.x;
  const int wid = tid >> 6;
  const int l = tid & 63;
  const int ln15 = l & 15;
  const int kg = l >> 4;
  const int u_wave = half * 128 + wid * 16;

  __shared__ unsigned short h_lds[32 * 256];   // [n][k] bf16, XOR-swizzled
  __shared__ float h_ex[128][33];              // own-half h, padded

  int* myflag = flags + dir * 2 + half;
  int* peerflag = flags + dir * 2 + (half ^ 1);

  // ---- W_hh A-fragments into registers (once) ----
  const float* Wh = dir ? Wbw : Wfw;
  short8 afrag[4][8];
  {
    int gate = ln15 & 3, du = ln15 >> 2;
#pragma unroll
    for (int mt = 0; mt < 4; ++mt) {
      int row = gate * 256 + u_wave + mt * 4 + du;
      const float* wr = Wh + (size_t)row * 256;
#pragma unroll
      for (int kc = 0; kc < 8; ++kc) {
        short8 f;
#pragma unroll
        for (int j = 0; j < 8; ++j) f[j] = bf16c(wr[kc * 32 + kg * 8 + j]);
        afrag[mt][kc] = f;
      }
    }
  }

  const float* xgd = xgT + (size_t)dir * (GROWS * 2048u);
  float cst[4][2] = {};
  f32x4 acc[4][2];

  // preload xg for step 0
  {
    int t0 = dir ? 63 : 0;
#pragma unroll
    for (int mt = 0; mt < 4; ++mt) {
      int unit = u_wave + mt * 4 + kg;
#pragma unroll
      for (int nt = 0; nt < 2; ++nt) {
        const float* xp = xgd + (size_t)unit * 2048 + t0 * NSEQ + nt * 16 + ln15;
#pragma unroll
        for (int j = 0; j < 4; ++j) acc[mt][nt][j] = xp[(size_t)j * 256 * 2048];
      }
    }
  }

  const int st_n = tid >> 4;           // 0..31
  const int st_k0 = (tid & 15) * 16;   // 0..240

  for (int s = 0; s < TSTEPS; ++s) {
    const int t = dir ? (63 - s) : s;

    if (s > 0) {
      if (tid == 0) {
        while (__hip_atomic_load(peerflag, __ATOMIC_ACQUIRE, __HIP_MEMORY_SCOPE_AGENT) < s)
          __builtin_amdgcn_s_sleep(1);
      }
      __syncthreads();
      // ---- stage h_{t_prev} (full 256) from hcat -> LDS bf16 swizzled ----
      {
        const int t_prev = dir ? (t + 1) : (t - 1);
        const float* src = hcat + ((size_t)t_prev * NSEQ + st_n) * 512 + dir * 256 + st_k0;
        char* dst = (char*)h_lds + st_n * 512;
        int swz = (st_n & 7) << 4;
        float4 a = *(const float4*)(src);
        float4 b = *(const float4*)(src + 4);
        float4 c = *(const float4*)(src + 8);
        float4 d = *(const float4*)(src + 12);
        short8 u0, u1;
        u0[0] = bf16c(a.x); u0[1] = bf16c(a.y); u0[2] = bf16c(a.z); u0[3] = bf16c(a.w);
        u0[4] = bf16c(b.x); u0[5] = bf16c(b.y); u0[6] = bf16c(b.z); u0[7] = bf16c(b.w);
        u1[0] = bf16c(c.x); u1[1] = bf16c(c.y); u1[2] = bf16c(c.z); u1[3] = bf16c(c.w);
        u1[4] = bf16c(d.x); u1[5] = bf16c(d.y); u1[6] = bf16c(d.z); u1[7] = bf16c(d.w);
        *(short8*)(dst + ((st_k0 * 2) ^ swz)) = u0;
        *(short8*)(dst + ((st_k0 * 2 + 16) ^ swz)) = u1;
      }
      __syncthreads();

      // ---- MFMA: gates += W_hh * h_prev ----
#pragma unroll
      for (int kc = 0; kc < 8; ++kc) {
        int kbyte = kc * 64 + kg * 16;
        int n0r = ln15, n1r = 16 + ln15;
        short8 b0 = *(const short8*)((const char*)h_lds + n0r * 512 + (kbyte ^ ((n0r & 7) << 4)));
        short8 b1 = *(const short8*)((const char*)h_lds + n1r * 512 + (kbyte ^ ((n1r & 7) << 4)));
#pragma unroll
        for (int mt = 0; mt < 4; ++mt) {
          acc[mt][0] = __builtin_amdgcn_mfma_f32_16x16x32_bf16(afrag[mt][kc], b0, acc[mt][0], 0, 0, 0);
          acc[mt][1] = __builtin_amdgcn_mfma_f32_16x16x32_bf16(afrag[mt][kc], b1, acc[mt][1], 0, 0, 0);
        }
      }
    }

    // ---- LSTM cell (lane-local; c in registers) ----
#pragma unroll
    for (int mt = 0; mt < 4; ++mt) {
#pragma unroll
      for (int nt = 0; nt < 2; ++nt) {
        float gi = sigm(acc[mt][nt][0]);
        float gf = sigm(acc[mt][nt][1]);
        float gg = tanh_fast(acc[mt][nt][2]);
        float go = sigm(acc[mt][nt][3]);
        float c = gf * cst[mt][nt] + gi * gg;
        cst[mt][nt] = c;
        float h = go * tanh_fast(c);
        h_ex[wid * 16 + mt * 4 + kg][nt * 16 + ln15] = h;
      }
    }
    __syncthreads();

    // ---- coalesced hcat write of own half (512B contiguous per row) ----
    {
      int wn = tid >> 4;            // 0..31
      int wu = (tid & 15) * 8;      // 0..120
      float4 v0, v1;
      v0.x = h_ex[wu + 0][wn]; v0.y = h_ex[wu + 1][wn];
      v0.z = h_ex[wu + 2][wn]; v0.w = h_ex[wu + 3][wn];
      v1.x = h_ex[wu + 4][wn]; v1.y = h_ex[wu + 5][wn];
      v1.z = h_ex[wu + 6][wn]; v1.w = h_ex[wu + 7][wn];
      float* dst = hcat + ((size_t)t * NSEQ + wn) * 512 + dir * 256 + half * 128 + wu;
      *(float4*)dst = v0;
      *(float4*)(dst + 4) = v1;
    }
    __syncthreads();

    if (tid == 0)
      __hip_atomic_store(myflag, s + 1, __ATOMIC_RELEASE, __HIP_MEMORY_SCOPE_AGENT);

    // ---- prefetch next-step xg into acc (overlaps peer poll) ----
    if (s < TSTEPS - 1) {
      int tn = dir ? (62 - s) : (s + 1);
#pragma unroll
      for (int mt = 0; mt < 4; ++mt) {
        int unit = u_wave + mt * 4 + kg;
#pragma unroll
        for (int nt = 0; nt < 2; ++nt) {
          const float* xp = xgd + (size_t)unit * 2048 + tn * NSEQ + nt * 16 + ln15;
#pragma unroll
          for (int j = 0; j < 4; ++j) acc[mt][nt][j] = xp[(size_t)j * 256 * 2048];
        }
      }
    }
  }
}

// ---------------- fused log-softmax + CTC loss ----------------
#define CTC_S 17
__global__ __launch_bounds__(576) void ctc_kernel(
    const float* __restrict__ preds,   // [64][32][12]
    const int* __restrict__ text,      // [256]
    const int* __restrict__ text_len,  // [32]
    float* __restrict__ out) {
  __shared__ float alpha[NSEQ][CTC_S];
  __shared__ float nalpha[NSEQ][CTC_S];
  __shared__ float lse[NSEQ];
  __shared__ int ext[NSEQ][CTC_S];
  __shared__ unsigned char allow[NSEQ][CTC_S];
  __shared__ unsigned char validm[NSEQ][CTC_S];
  __shared__ int tlsh[NSEQ];
  __shared__ float logp_sh[NSEQ];

  int tid = threadIdx.x;
  int b = tid & 31, sIdx = tid >> 5;
  bool active = sIdx < CTC_S;

  if (tid < NSEQ) tlsh[tid] = text_len[tid];
  __syncthreads();

  if (active) {
    int tl = tlsh[b];
    int off = 0;
    for (int i = 0; i < b; ++i) off += tlsh[i];
    int e = 0;
    if (sIdx & 1) {
      int lbl = (sIdx - 1) >> 1;
      int idx = off + lbl;
      if (idx > 255) idx = 255;
      e = (lbl < tl) ? text[idx] : 0;
    }
    ext[b][sIdx] = e;
    validm[b][sIdx] = (sIdx < 2 * tl + 1) ? 1 : 0;
  }
  __syncthreads();
  if (active) {
    int e = ext[b][sIdx];
    bool same2 = (sIdx >= 2) && (e == ext[b][sIdx - 2]);
    allow[b][sIdx] = ((sIdx >= 2) && (e != 0) && !same2) ? 1 : 0;
  }
  if (tid < NSEQ) {
    const float* p = preds + (size_t)b * 12;
    float mx = p[0];
    for (int k = 1; k < 12; ++k) mx = fmaxf(mx, p[k]);
    float ssum = 0.f;
    for (int k = 0; k < 12; ++k) ssum += expf(p[k] - mx);
    lse[b] = mx + logf(ssum);
  }
  __syncthreads();
  if (active) {
    float a = -1e30f;
    if (sIdx == 0) a = preds[(size_t)b * 12 + 0] - lse[b];
    else if (sIdx == 1 && tlsh[b] > 0) a = preds[(size_t)b * 12 + ext[b][1]] - lse[b];
    alpha[b][sIdx] = a;
  }
  __syncthreads();

  for (int t = 1; t < TSTEPS; ++t) {
    if (tid < NSEQ) {
      const float* p = preds + ((size_t)t * NSEQ + b) * 12;
      float mx = p[0];
      for (int k = 1; k < 12; ++k) mx = fmaxf(mx, p[k]);
      float ssum = 0.f;
      for (int k = 0; k < 12; ++k) ssum += expf(p[k] - mx);
      lse[b] = mx + logf(ssum);
    }
    __syncthreads();
    if (active) {
      float a = alpha[b][sIdx];
      float a1 = (sIdx >= 1) ? alpha[b][sIdx - 1] : -1e30f;
      float a2 = (sIdx >= 2 && allow[b][sIdx]) ? alpha[b][sIdx - 2] : -1e30f;
      float m = fmaxf(a, fmaxf(a1, a2));
      float ssum = expf(a - m) + expf(a1 - m) + expf(a2 - m);
      float emit = preds[((size_t)t * NSEQ + b) * 12 + ext[b][sIdx]] - lse[b];
      float nv = m + logf(ssum) + emit;
      nalpha[b][sIdx] = validm[b][sIdx] ? nv : -1e30f;
    }
    __syncthreads();
    if (active) alpha[b][sIdx] = nalpha[b][sIdx];
    __syncthreads();
  }

  if (tid < NSEQ) {
    int tl = tlsh[b];
    float a1 = alpha[b][2 * tl];
    float a2 = (tl > 0) ? alpha[b][2 * tl - 1] : -1e30f;
    float m = fmaxf(a1, a2);
    logp_sh[b] = m + logf(expf(a1 - m) + expf(a2 - m));
  }
  __syncthreads();
  if (tid == 0) {
    float ssum = 0.f;
    for (int i = 0; i < NSEQ; ++i) ssum += logp_sh[i];
    out[0] = -ssum / (float)NSEQ;
  }
}

// ---------------- launch ----------------
extern "C" void kernel_launch(void* const* d_in, const int* in_sizes, int n_in,
                              void* d_out, int out_size, void* d_ws, size_t ws_size,
                              hipStream_t stream) {
  (void)in_sizes; (void)n_in; (void)out_size; (void)ws_size;
  const float* base_feat = (const float*)d_in[0];
  const int* text = (const int*)d_in[1];
  const int* text_len = (const int*)d_in[2];
  const float* rois = (const float*)d_in[3];
  const float* l1_fw_W_ih = (const float*)d_in[4];
  const float* l1_fw_W_hh = (const float*)d_in[5];
  const float* l1_fw_b_ih = (const float*)d_in[6];
  const float* l1_fw_b_hh = (const float*)d_in[7];
  const float* l1_bw_W_ih = (const float*)d_in[8];
  const float* l1_bw_W_hh = (const float*)d_in[9];
  const float* l1_bw_b_ih = (const float*)d_in[10];
  const float* l1_bw_b_hh = (const float*)d_in[11];
  const float* l2_fw_W_ih = (const float*)d_in[12];
  const float* l2_fw_W_hh = (const float*)d_in[13];
  const float* l2_fw_b_ih = (const float*)d_in[14];
  const float* l2_fw_b_hh = (const float*)d_in[15];
  const float* l2_bw_W_ih = (const float*)d_in[16];
  const float* l2_bw_W_hh = (const float*)d_in[17];
  const float* l2_bw_b_ih = (const float*)d_in[18];
  const float* l2_bw_b_hh = (const float*)d_in[19];
  const float* W_emb1 = (const float*)d_in[20];
  const float* b_emb1 = (const float*)d_in[21];
  const float* W_emb2 = (const float*)d_in[22];
  const float* b_emb2 = (const float*)d_in[23];

  float* ws = (float*)d_ws;
  float* rnn   = ws + OFF_RNN;
  float* xg    = ws + OFF_XG;
  float* hcat1 = ws + OFF_HCAT1;
  float* h1    = ws + OFF_H1;
  float* hcat2 = ws + OFF_HCAT2;
  float* preds = ws + OFF_PREDS;
  int*   bar   = (int*)(ws + OFF_BAR);

  hipMemsetAsync(bar, 0, 16 * sizeof(int), stream);

  // 1) ROI max pool -> rnn_in [2048][1024]
  roi_pool_kernel<<<dim3(32, 256), 256, 0, stream>>>(base_feat, rois, rnn);

  // 2) xg layer1
  gemm_nt<<<dim3(32, 16), 256, 0, stream>>>(l1_fw_W_ih, rnn, xg,
      1024, 2048, 1024, l1_fw_b_ih, l1_fw_b_hh, nullptr);
  gemm_nt<<<dim3(32, 16), 256, 0, stream>>>(l1_bw_W_ih, rnn, xg + 2097152u,
      1024, 2048, 1024, l1_bw_b_ih, l1_bw_b_hh, nullptr);

  // 3) layer-1 recurrence (persistent, 4 blocks, 2-party barriers)
  lstm_layer2<<<4, 512, 0, stream>>>(xg, l1_fw_W_hh, l1_bw_W_hh, hcat1, bar);

  // 4) h1 = hcat1 @ W_emb1^T + b_emb1
  gemm_nt<<<dim3(4, 32), 256, 0, stream>>>(hcat1, W_emb1, h1,
      2048, 256, 512, nullptr, nullptr, b_emb1);

  // 5) xg layer2
  gemm_nt<<<dim3(32, 16), 256, 0, stream>>>(l2_fw_W_ih, h1, xg,
      1024, 2048, 256, l2_fw_b_ih, l2_fw_b_hh, nullptr);
  gemm_nt<<<dim3(32, 16), 256, 0, stream>>>(l2_bw_W_ih, h1, xg + 2097152u,
      1024, 2048, 256, l2_bw_b_ih, l2_bw_b_hh, nullptr);

  // 6) layer-2 recurrence
  lstm_layer2<<<4, 512, 0, stream>>>(xg, l2_fw_W_hh, l2_bw_W_hh, hcat2, bar + 4);

  // 7) preds = hcat2 @ W_emb2^T + b_emb2
  gemm_nt<<<dim3(1, 32), 256, 0, stream>>>(hcat2, W_emb2, preds,
      2048, 12, 512, nullptr, nullptr, b_emb2);

  // 8) log-softmax + CTC
  ctc_kernel<<<1, 576, 0, stream>>>(preds, text, text_len, (float*)d_out);
}